// Round 4
// baseline (2901.036 us; speedup 1.0000x reference)
//
#include <hip/hip_runtime.h>
#include <math.h>

typedef unsigned short u16;
typedef unsigned int   u32;

#define B_   32
#define S_   200
#define D_   128
#define T_   199
#define NEGV (-1e30f)

__device__ __forceinline__ float bf2f(u16 u){
  union { u32 i; float f; } v; v.i = ((u32)u) << 16; return v.f;
}
__device__ __forceinline__ u16 f2bf(float f){
  union { float f; u32 i; } v; v.f = f;
  u32 x = v.i;
  return (u16)((x + 0x7fffu + ((x >> 16) & 1u)) >> 16);   // RNE
}
__device__ __forceinline__ float lo_(u32 u){
  union { u32 i; float f; } v; v.i = u << 16; return v.f;
}
__device__ __forceinline__ float hi_(u32 u){
  union { u32 i; float f; } v; v.i = u & 0xffff0000u; return v.f;
}
__device__ __forceinline__ float fast_sigmoid(float x){ return 1.f/(1.f+__expf(-x)); }
__device__ __forceinline__ float fast_tanh(float x){
  float e = __expf(2.f*x);
  return 1.f - 2.f/(e + 1.f);
}

// bool storage modes: 0=int32, 1=u8, 2=bf16, 3=f32
__device__ __forceinline__ int readBool(const void* p, int i, int m){
  if (m == 0) return ((const int*)p)[i] != 0;
  if (m == 1) return ((const unsigned char*)p)[i] != 0;
  if (m == 2) return ((const u16*)p)[i] != 0;
  return ((const u32*)p)[i] != 0;
}

__device__ __forceinline__ float dot128f(const float* __restrict__ w,
                                         const float* __restrict__ x){
  float acc = 0.f;
  const float4* wp = (const float4*)w;
  #pragma unroll 8
  for (int i = 0; i < 32; i++){
    float4 v = wp[i]; int k = 4*i;
    acc = fmaf(v.x, x[k],   acc);
    acc = fmaf(v.y, x[k+1], acc);
    acc = fmaf(v.z, x[k+2], acc);
    acc = fmaf(v.w, x[k+3], acc);
  }
  return acc;
}

// ---------------------------------------------------------------- sniffer
__global__ void k_sniff2(const u16* __restrict__ embq_raw,
                         const unsigned char* __restrict__ mask_raw,
                         int* __restrict__ flags){
  __shared__ int bad, gt1, m4, b0;
  const int tid = threadIdx.x;
  if (tid == 0){ bad = 0; gt1 = 0; m4 = 0; b0 = 0; }
  __syncthreads();
  for (int i = tid; i < 512; i += 256){
    u16 u = embq_raw[i];
    if (u){ int e = (u >> 7) & 0xFF; if (e < 0x58 || e > 0x7F) atomicAdd(&bad, 1); }
  }
  for (int i = tid; i < 1024; i += 256){
    unsigned char c = mask_raw[i];
    if (c > 1) atomicAdd(&gt1, 1);
    if (c && (i & 3)) atomicAdd(&m4, 1);
    if (c && !(i & 3)) atomicAdd(&b0, 1);
  }
  __syncthreads();
  if (tid == 0){
    flags[0] = (bad >= 16) ? 1 : 0;
    flags[1] = gt1 ? (b0 ? 2 : 3) : (m4 ? 1 : 0);
  }
}

// ---------------------------------------------------------------- convert floats -> f32
#define NCVT 23
struct CvtArgs { const void* s[NCVT]; int off[NCVT+1]; int nreal[NCVT]; };

__global__ void k_cvt(CvtArgs a, const int* __restrict__ flags, float* __restrict__ dst){
  __shared__ int f;
  if (threadIdx.x == 0) f = flags[0];
  __syncthreads();
  int gid = blockIdx.x * 256 + threadIdx.x;
  if (gid >= a.off[NCVT]) return;
  int ai = 0;
  for (int i = 1; i < NCVT; i++) if (gid >= a.off[i]) ai = i;
  int i = gid - a.off[ai];
  float v = 0.f;
  if (i < a.nreal[ai])
    v = f ? ((const float*)a.s[ai])[i] : bf2f(((const u16*)a.s[ai])[i]);
  dst[gid] = v;
}

// ---------------------------------------------------------------- K1: hop aggregation
template<int ROWS>
__device__ __forceinline__ void agg_stage(const float* __restrict__ tmp,
    const float* __restrict__ Wg, const float* __restrict__ bg,
    float* __restrict__ outbuf, int tid)
{
  const int c = tid & 127;
  const int half = tid >> 7;
  constexpr int NR = (ROWS + 1) / 2;
  const bool active = !(ROWS == 1 && half == 1);
  float bias = bg[c];
  float acc[NR];
  #pragma unroll
  for (int i = 0; i < NR; i++) acc[i] = bias;
  if (active){
    const float4* wp = (const float4*)(Wg + c*128);
    #pragma unroll 4
    for (int i4 = 0; i4 < 32; i4++){
      float4 wv = wp[i4];
      int kk = 4*i4;
      #pragma unroll
      for (int i = 0; i < NR; i++){
        int r = (ROWS == 1) ? 0 : (half + 2*i);
        float4 t4 = *(const float4*)(tmp + r*128 + kk);
        acc[i] = fmaf(t4.x, wv.x, acc[i]);
        acc[i] = fmaf(t4.y, wv.y, acc[i]);
        acc[i] = fmaf(t4.z, wv.z, acc[i]);
        acc[i] = fmaf(t4.w, wv.w, acc[i]);
      }
    }
    #pragma unroll
    for (int i = 0; i < NR; i++){
      int r = (ROWS == 1) ? 0 : (half + 2*i);
      outbuf[r*128 + c] = fast_tanh(acc[i]);
    }
  }
}

__launch_bounds__(256, 4)
__global__ void k_agg(const int* __restrict__ question,
                      const int* __restrict__ q_neighbors,
                      const int* __restrict__ s_neighbors,
                      const float* __restrict__ EQ,
                      const float* __restrict__ EC,
                      const float* __restrict__ AW,
                      const float* __restrict__ AB,
                      const float* __restrict__ ALW,
                      const float* __restrict__ ALB,
                      const void* __restrict__ maskp,
                      const int* __restrict__ flags,
                      float* __restrict__ EQREC)
{
  __shared__ __align__(16) float e0[128];
  __shared__ __align__(16) float e1[512];
  __shared__ __align__(16) float e2[2048];
  __shared__ __align__(16) float tmp[2048];
  __shared__ int nn1[4]; __shared__ int nn2[16]; __shared__ int nn3[64];
  const int tid = threadIdx.x;
  const int bs  = blockIdx.x;
  const int n0  = question[bs];
  if (tid < 4)  nn1[tid] = q_neighbors[n0*4 + tid];
  __syncthreads();
  if (tid < 16) nn2[tid] = s_neighbors[nn1[tid>>2]*4 + (tid&3)];
  __syncthreads();
  if (tid < 64) nn3[tid] = q_neighbors[nn2[tid>>2]*4 + (tid&3)];
  for (int o = tid; o < 128; o += 256)  e0[o] = EQ[n0*128 + o];
  __syncthreads();
  for (int o = tid; o < 512; o += 256)  e1[o] = EC[nn1[o>>7]*128 + (o&127)];
  for (int o = tid; o < 2048; o += 256) e2[o] = EQ[nn2[o>>7]*128 + (o&127)];
  __syncthreads();

  auto fill_e0 = [&](){
    for (int o = tid; o < 128; o += 256)
      tmp[o] = 0.25f*(e1[o] + e1[128+o] + e1[256+o] + e1[384+o]) + e0[o];
  };
  auto fill_e1 = [&](){
    for (int o = tid; o < 512; o += 256){
      int r = o >> 7, k = o & 127;
      tmp[o] = 0.25f*(e2[(4*r)*128+k] + e2[(4*r+1)*128+k]
                    + e2[(4*r+2)*128+k] + e2[(4*r+3)*128+k]) + e1[o];
    }
  };

  // i=0: j=0,1,2
  fill_e0(); __syncthreads();
  agg_stage<1>(tmp, AW, AB, e0, tid); __syncthreads();
  fill_e1(); __syncthreads();
  agg_stage<4>(tmp, AW + 16384, AB + 128, e1, tid); __syncthreads();
  for (int o = tid; o < 2048; o += 256){
    int r = o >> 7, k = o & 127;
    float m = 0.25f*( EC[nn3[4*r]*128+k]   + EC[nn3[4*r+1]*128+k]
                    + EC[nn3[4*r+2]*128+k] + EC[nn3[4*r+3]*128+k] );
    tmp[o] = m + e2[o];
  }
  __syncthreads();
  agg_stage<16>(tmp, AW + 32768, AB + 256, e2, tid); __syncthreads();
  // i=1: j=0,1
  fill_e0(); __syncthreads();
  agg_stage<1>(tmp, AW, AB, e0, tid); __syncthreads();
  fill_e1(); __syncthreads();
  agg_stage<4>(tmp, AW + 16384, AB + 128, e1, tid); __syncthreads();
  // i=2: j=0
  fill_e0(); __syncthreads();
  agg_stage<1>(tmp, AW, AB, e0, tid); __syncthreads();
  agg_stage<1>(e0, ALW, ALB, tmp, tid); __syncthreads();
  const int msk = readBool(maskp, bs, flags[1]);
  for (int o = tid; o < 128; o += 256)
    EQREC[bs*128 + o] = msk ? tmp[o] : EQ[n0*128 + o];
}

// ---------------------------------------------------------------- K2: gi1 precompute
__launch_bounds__(384, 1)
__global__ void k_gi1(const float* __restrict__ EQREC,
                      const int* __restrict__ response,
                      const float* __restrict__ ECOR,
                      const float* __restrict__ WIH1,
                      const float* __restrict__ BIH1,
                      float* __restrict__ GI1)
{
  const int t  = blockIdx.x;
  const int bg = blockIdx.y;
  const int tid = threadIdx.x;
  __shared__ __align__(16) float X[8][256];
  for (int o = tid; o < 2048; o += 384){
    int bb = o >> 8, k = o & 255;
    int b = bg*8 + bb;
    X[bb][k] = (k < 128) ? EQREC[(b*S_ + t)*128 + k]
                         : ECOR[response[b*S_ + t]*128 + (k - 128)];
  }
  __syncthreads();
  float bias = BIH1[tid];
  float acc[8];
  #pragma unroll
  for (int i = 0; i < 8; i++) acc[i] = bias;
  const float4* wp = (const float4*)(WIH1 + tid*256);
  #pragma unroll 2
  for (int i8 = 0; i8 < 64; i8 += 2){
    float4 v0 = wp[i8], v1 = wp[i8+1];
    float wv[8] = {v0.x,v0.y,v0.z,v0.w,v1.x,v1.y,v1.z,v1.w};
    int k0 = i8*4;
    #pragma unroll
    for (int bb = 0; bb < 8; bb++){
      #pragma unroll
      for (int kq = 0; kq < 8; kq++)
        acc[bb] = fmaf(X[bb][k0 + kq], wv[kq], acc[bb]);
    }
  }
  #pragma unroll
  for (int bb = 0; bb < 8; bb++)
    GI1[(t*32 + bg*8 + bb)*384 + tid] = acc[bb];
}

// ---------------------------------------------------------------- K3: scores + top-10
__global__ void k_topk(const int* __restrict__ question,
                       const float* __restrict__ EQ,
                       int* __restrict__ IDX)
{
  const int blk = blockIdx.x;
  const int t = blk >> 5, b = blk & 31;
  const int tid = threadIdx.x;               // 64
  __shared__ __align__(16) float qn[128];
  const int qid = question[b*S_ + t + 1];
  for (int o = tid; o < 128; o += 64) qn[o] = EQ[qid*128 + o];
  __syncthreads();
  float val[4]; int sv[4];
  #pragma unroll
  for (int i = 0; i < 4; i++){
    int s = tid + 64*i;
    sv[i] = s;
    float v = -3.0e38f;
    if (s < S_) v = (s < t) ? dot128f(EQ + question[b*S_ + s]*128, qn) : NEGV;
    val[i] = v;
  }
  for (int r = 0; r < 10; r++){
    float bv = -3.0e38f; int bi = 0x3fffffff;
    #pragma unroll
    for (int i = 0; i < 4; i++){
      if (val[i] > bv || (val[i] == bv && sv[i] < bi)){ bv = val[i]; bi = sv[i]; }
    }
    for (int off = 32; off; off >>= 1){
      float ov = __shfl_down(bv, off);
      int   oi = __shfl_down(bi, off);
      if (ov > bv || (ov == bv && oi < bi)){ bv = ov; bi = oi; }
    }
    int win = __shfl(bi, 0);
    if (tid == 0) IDX[blk*10 + r] = win;
    #pragma unroll
    for (int i = 0; i < 4; i++) if (sv[i] == win) val[i] = -3.0e38f;
  }
}

// ---------------------------------------------------------------- K4: sequential GRU chain
// Weights in VGPRs as packed bf16 (192 u32). __launch_bounds__(384,1) keeps
// the wave VGPR budget at 256 (1 block/CU, max 2 waves/SIMD) -> NO SPILL.
// (384,2) forced a 128-VGPR cap and spilled ~9.4 MB/step to scratch (r3).
__launch_bounds__(384, 1)
__global__ void k_gru(const float* __restrict__ GI1,
                      const float* __restrict__ WHH1, const float* __restrict__ BHH1,
                      const float* __restrict__ WIH2, const float* __restrict__ BIH2,
                      const float* __restrict__ WHH2, const float* __restrict__ BHH2,
                      const float* __restrict__ H1I, const float* __restrict__ H2I,
                      float* __restrict__ G2)
{
  const int b = blockIdx.x;
  const int tid = threadIdx.x;
  __shared__ __align__(16) float h1[128];
  __shared__ __align__(16) float h2[128];
  __shared__ float gh1[384], gh2[384], gi2s[384];
  if (tid < 128){
    h1[tid] = H1I[b*128 + tid];
    h2[tid] = H2I[b*128 + tid];
  }
  const float bh1 = BHH1[tid];
  const float bh2 = BHH2[tid];
  const float bi2 = BIH2[tid];
  u32 W1[64], W2[64], WI[64];
  {
    const float4* p1 = (const float4*)(WHH1 + tid*128);
    const float4* p2 = (const float4*)(WHH2 + tid*128);
    const float4* pi = (const float4*)(WIH2 + tid*128);
    #pragma unroll
    for (int i = 0; i < 32; i++){
      float4 a = p1[i], c = p2[i], d = pi[i];
      W1[2*i]   = ((u32)f2bf(a.y) << 16) | f2bf(a.x);
      W1[2*i+1] = ((u32)f2bf(a.w) << 16) | f2bf(a.z);
      W2[2*i]   = ((u32)f2bf(c.y) << 16) | f2bf(c.x);
      W2[2*i+1] = ((u32)f2bf(c.w) << 16) | f2bf(c.z);
      WI[2*i]   = ((u32)f2bf(d.y) << 16) | f2bf(d.x);
      WI[2*i+1] = ((u32)f2bf(d.w) << 16) | f2bf(d.z);
    }
  }
  // prefetch GI1 for t=0
  float irN = 0.f, izN = 0.f, innN = 0.f;
  if (tid < 128){
    const float* gp = GI1 + (0*32 + b)*384;
    irN = gp[tid]; izN = gp[128+tid]; innN = gp[256+tid];
  }
  __syncthreads();
  for (int t = 0; t < T_; t++){
    const float ir = irN, iz = izN, inn = innN;
    // prefetch GI1 for t+1 (consumed in next step's phase B -> long cover)
    if (t + 1 < T_ && tid < 128){
      const float* gp = GI1 + ((t+1)*32 + b)*384;
      irN = gp[tid]; izN = gp[128+tid]; innN = gp[256+tid];
    }
    // phase A: gh1 = bhh1 + h1@whh1.T ; gh2 = bhh2 + h2@whh2.T
    float a1 = bh1, a1b = 0.f, a2 = bh2, a2b = 0.f;
    #pragma unroll
    for (int i = 0; i < 32; i++){
      const float4 hv1 = *(const float4*)(h1 + 4*i);
      const float4 hv2 = *(const float4*)(h2 + 4*i);
      u32 ua = W1[2*i], ub = W1[2*i+1];
      u32 uc = W2[2*i], ud = W2[2*i+1];
      a1  = fmaf(lo_(ua), hv1.x, a1);
      a1b = fmaf(hi_(ua), hv1.y, a1b);
      a1  = fmaf(lo_(ub), hv1.z, a1);
      a1b = fmaf(hi_(ub), hv1.w, a1b);
      a2  = fmaf(lo_(uc), hv2.x, a2);
      a2b = fmaf(hi_(uc), hv2.y, a2b);
      a2  = fmaf(lo_(ud), hv2.z, a2);
      a2b = fmaf(hi_(ud), hv2.w, a2b);
    }
    gh1[tid] = a1 + a1b; gh2[tid] = a2 + a2b;
    __syncthreads();
    // phase B: h1 gates
    if (tid < 128){
      float r = fast_sigmoid(ir + gh1[tid]);
      float z = fast_sigmoid(iz + gh1[128+tid]);
      float n = fast_tanh(inn + r*gh1[256+tid]);
      h1[tid] = (1.f - z)*n + z*h1[tid];
    }
    __syncthreads();
    // phase C: gi2 = bih2 + h1_new@wih2.T
    float ai = bi2, aib = 0.f;
    #pragma unroll
    for (int i = 0; i < 32; i++){
      const float4 hv = *(const float4*)(h1 + 4*i);
      u32 ua = WI[2*i], ub = WI[2*i+1];
      ai  = fmaf(lo_(ua), hv.x, ai);
      aib = fmaf(hi_(ua), hv.y, aib);
      ai  = fmaf(lo_(ub), hv.z, ai);
      aib = fmaf(hi_(ub), hv.w, aib);
    }
    gi2s[tid] = ai + aib;
    __syncthreads();
    // phase D: g2 gates; h2 update skipped at t==0
    if (tid < 128){
      float r2 = fast_sigmoid(gi2s[tid] + gh2[tid]);
      float z2 = fast_sigmoid(gi2s[128+tid] + gh2[128+tid]);
      float n2 = fast_tanh(gi2s[256+tid] + r2*gh2[256+tid]);
      float g = (1.f - z2)*n2 + z2*h2[tid];
      G2[(t*32 + b)*128 + tid] = g;
      if (t > 0) h2[tid] = g;
    }
    __syncthreads();
  }
}

// ---------------------------------------------------------------- K5: Qp·w_q and Kp·w_k scalars
__device__ __forceinline__ float blockReduce128(float v, float* red, int tid){
  for (int off = 32; off; off >>= 1) v += __shfl_down(v, off);
  if ((tid & 63) == 0) red[tid >> 6] = v;
  __syncthreads();
  float r = red[0] + red[1];
  __syncthreads();
  return r;
}

__global__ void k_qkw(const int* __restrict__ question,
                      const int* __restrict__ qci,
                      const void* __restrict__ qcm,
                      const int* __restrict__ flags,
                      const float* __restrict__ EQ,
                      const float* __restrict__ EC,
                      const float* __restrict__ KW, const float* __restrict__ KB,
                      const float* __restrict__ QW, const float* __restrict__ QB,
                      const float* __restrict__ MW,
                      const float* __restrict__ G2,
                      float* __restrict__ QPW, float* __restrict__ KPWG)
{
  const int blk = blockIdx.x;
  const int t = blk >> 5, b = blk & 31;
  const int tid = threadIdx.x;               // 128
  __shared__ __align__(16) float row[128];
  __shared__ float red[2];
  const int qid = question[b*S_ + t + 1];
  const int bflag = flags[1];
  #pragma unroll 1
  for (int q = 0; q < 5; q++){
    float v = 0.f;
    if (q == 0) v = EQ[qid*128 + tid];
    else if (readBool(qcm, qid*4 + q - 1, bflag))
      v = EC[qci[qid*4 + q - 1]*128 + tid];
    __syncthreads();
    row[tid] = v;
    __syncthreads();
    float acc = KB[tid] + dot128f(KW + tid*128, row);
    float pv  = fast_tanh(acc) * MW[tid];              // w_q
    float s = blockReduce128(pv, red, tid);
    if (tid == 0) QPW[blk*5 + q] = s;
  }
  __syncthreads();
  row[tid] = G2[blk*128 + tid];
  __syncthreads();
  float acc = QB[tid] + dot128f(QW + tid*128, row);
  float pv  = fast_tanh(acc) * MW[128 + tid];          // w_k
  float s = blockReduce128(pv, red, tid);
  if (tid == 0) KPWG[blk] = s;
}

// ---------------------------------------------------------------- K6: predict + output
__global__ void k_pred(const int* __restrict__ question,
                       const int* __restrict__ qci, const void* __restrict__ qcm,
                       const int* __restrict__ flags,
                       const float* __restrict__ EQ, const float* __restrict__ EC,
                       const float* __restrict__ QB, const float* __restrict__ MW,
                       const float* __restrict__ MB,
                       const float* __restrict__ G2,
                       const int* __restrict__ IDX,
                       const float* __restrict__ QPW, const float* __restrict__ KPWG,
                       void* __restrict__ outp)
{
  const int blk = blockIdx.x;
  const int t = blk >> 5, b = blk & 31;
  const int tid = threadIdx.x;               // 64
  __shared__ float hist[11][132];
  __shared__ float qc[5][132];
  __shared__ float og[55];
  __shared__ float kpw[11];
  __shared__ int   idxs[10];
  __shared__ float kpw0s;
  __shared__ float pq[5];
  const int qid = question[b*S_ + t + 1];
  const int bflag = flags[1];
  if (tid < 10) idxs[tid] = IDX[blk*10 + tid];
  __syncthreads();
  for (int o = tid; o < 11*128; o += 64){
    int k = o >> 7, c = o & 127;
    float v;
    if (k == 0) v = G2[blk*128 + c];
    else { int s = idxs[k-1]; v = (s == 0) ? 0.f : G2[(s*32 + b)*128 + c]; }
    hist[k][c] = v;
  }
  for (int o = tid; o < 5*128; o += 64){
    int q = o >> 7, c = o & 127;
    float v = 0.f;
    if (q == 0) v = EQ[qid*128 + c];
    else if (readBool(qcm, qid*4 + q - 1, bflag))
      v = EC[qci[qid*4 + q - 1]*128 + c];
    qc[q][c] = v;
  }
  {
    float pv = fast_tanh(QB[tid])      * MW[128 + tid]
             + fast_tanh(QB[tid + 64]) * MW[128 + tid + 64];
    for (int off = 32; off; off >>= 1) pv += __shfl_down(pv, off);
    if (tid == 0) kpw0s = pv;
  }
  __syncthreads();
  if (tid < 55){
    int q = tid / 11, k = tid % 11;
    float acc = 0.f;
    for (int c = 0; c < 128; c++) acc = fmaf(qc[q][c], hist[k][c], acc);
    og[tid] = acc;
  }
  if (tid < 11){
    float v;
    if (tid == 0) v = KPWG[blk];
    else { int s = idxs[tid-1]; v = (s == 0) ? kpw0s : KPWG[s*32 + b]; }
    kpw[tid] = v;
  }
  __syncthreads();
  if (tid < 5){
    float qw = QPW[blk*5 + tid];
    float bb = MB[0];
    float tv[11];
    #pragma unroll
    for (int k = 0; k < 11; k++){
      int valid = (k == 0) || (idxs[k-1] < t);
      tv[k] = valid ? (qw + kpw[k] + bb) : NEGV;
    }
    float m = tv[0];
    #pragma unroll
    for (int k = 1; k < 11; k++) m = fmaxf(m, tv[k]);
    float den = 0.f, num = 0.f;
    #pragma unroll
    for (int k = 0; k < 11; k++){
      float e = __expf(tv[k] - m);
      den += e;
      num = fmaf(e, og[tid*11 + k], num);
    }
    pq[tid] = num / den;
  }
  __syncthreads();
  if (tid == 0){
    float p = pq[0] + pq[1] + pq[2] + pq[3] + pq[4];
    int col = (t == 0) ? 0 : (t + 1);
    if (flags[0]){
      ((float*)outp)[b*S_ + col] = p;
      if (t == 0) ((float*)outp)[b*S_ + 1] = 0.f;
    } else {
      ((u16*)outp)[b*S_ + col] = f2bf(p);
      if (t == 0) ((u16*)outp)[b*S_ + 1] = (u16)0;
    }
  }
}

// ---------------------------------------------------------------- launcher
extern "C" void kernel_launch(void* const* d_in, const int* in_sizes, int n_in,
                              void* d_out, int out_size, void* d_ws, size_t ws_size,
                              hipStream_t stream)
{
  (void)in_sizes; (void)n_in; (void)out_size; (void)ws_size;
  const int* question      = (const int*)d_in[0];
  const int* response      = (const int*)d_in[1];
  const void* maskp        = d_in[2];
  const int* q_neighbors   = (const int*)d_in[3];
  const int* s_neighbors   = (const int*)d_in[4];
  const int* q_concept_idx = (const int*)d_in[5];
  const void* q_concept_mask = d_in[6];

  static const int CN[NCVT] = {2560000,256000,256,98304,49152,384,384,49152,49152,
                               384,384,49152,384,16384,128,16384,128,16384,128,
                               256,1,4096,4096};
  CvtArgs ca;
  int off = 0;
  for (int i = 0; i < NCVT; i++){
    ca.s[i] = d_in[7 + i];
    ca.nreal[i] = CN[i];
    ca.off[i] = off;
    off += (CN[i] + 3) & ~3;
  }
  ca.off[NCVT] = off;
  const int total = off;

  char* ws = (char*)d_ws;
  size_t wo = 0;
  auto alloc = [&](size_t bytes) -> void* {
    void* p = ws + wo;
    wo = (wo + bytes + 255) & ~(size_t)255;
    return p;
  };
  int*   flags = (int*)  alloc(16);
  float* CVT   = (float*)alloc((size_t)total * 4);
  float* EQREC = (float*)alloc((size_t)B_*S_*D_*4);
  float* GI1   = (float*)alloc((size_t)T_*B_*384*4);
  float* G2    = (float*)alloc((size_t)T_*B_*D_*4);
  int*   IDX   = (int*)  alloc((size_t)T_*B_*10*4);
  float* QPW   = (float*)alloc((size_t)T_*B_*5*4);
  float* KPWG  = (float*)alloc((size_t)T_*B_*4);

  const float* EQ   = CVT + ca.off[0];
  const float* EC   = CVT + ca.off[1];
  const float* ECOR = CVT + ca.off[2];
  const float* WIH1 = CVT + ca.off[3];
  const float* WHH1 = CVT + ca.off[4];
  const float* BIH1 = CVT + ca.off[5];
  const float* BHH1 = CVT + ca.off[6];
  const float* WIH2 = CVT + ca.off[7];
  const float* WHH2 = CVT + ca.off[8];
  const float* BIH2 = CVT + ca.off[9];
  const float* BHH2 = CVT + ca.off[10];
  const float* AW   = CVT + ca.off[11];
  const float* AB   = CVT + ca.off[12];
  const float* ALW  = CVT + ca.off[13];
  const float* ALB  = CVT + ca.off[14];
  const float* QW   = CVT + ca.off[15];
  const float* QB   = CVT + ca.off[16];
  const float* KW   = CVT + ca.off[17];
  const float* KB   = CVT + ca.off[18];
  const float* MW   = CVT + ca.off[19];
  const float* MB   = CVT + ca.off[20];
  const float* H1I  = CVT + ca.off[21];
  const float* H2I  = CVT + ca.off[22];

  k_sniff2<<<1, 256, 0, stream>>>((const u16*)d_in[7], (const unsigned char*)maskp, flags);
  k_cvt<<<(total + 255)/256, 256, 0, stream>>>(ca, flags, CVT);
  k_agg<<<B_*S_, 256, 0, stream>>>(question, q_neighbors, s_neighbors, EQ, EC,
                                   AW, AB, ALW, ALB, maskp, flags, EQREC);
  k_gi1<<<dim3(T_, 4), 384, 0, stream>>>(EQREC, response, ECOR, WIH1, BIH1, GI1);
  k_topk<<<T_*B_, 64, 0, stream>>>(question, EQ, IDX);
  k_gru<<<B_, 384, 0, stream>>>(GI1, WHH1, BHH1, WIH2, BIH2, WHH2, BHH2,
                                H1I, H2I, G2);
  k_qkw<<<T_*B_, 128, 0, stream>>>(question, q_concept_idx, q_concept_mask, flags,
                                   EQ, EC, KW, KB, QW, QB, MW, G2, QPW, KPWG);
  k_pred<<<T_*B_, 64, 0, stream>>>(question, q_concept_idx, q_concept_mask, flags,
                                   EQ, EC, QB, MW, MB, G2, IDX, QPW, KPWG, d_out);
}

// Round 5
// 1400.657 us; speedup vs baseline: 2.0712x; 2.0712x over previous
//
#include <hip/hip_runtime.h>
#include <math.h>

typedef unsigned short u16;
typedef unsigned int   u32;

#define B_   32
#define S_   200
#define D_   128
#define T_   199
#define NEGV (-1e30f)

__device__ __forceinline__ float bf2f(u16 u){
  union { u32 i; float f; } v; v.i = ((u32)u) << 16; return v.f;
}
__device__ __forceinline__ u16 f2bf(float f){
  union { float f; u32 i; } v; v.f = f;
  u32 x = v.i;
  return (u16)((x + 0x7fffu + ((x >> 16) & 1u)) >> 16);   // RNE
}
__device__ __forceinline__ float lo_(u32 u){
  union { u32 i; float f; } v; v.i = u << 16; return v.f;
}
__device__ __forceinline__ float hi_(u32 u){
  union { u32 i; float f; } v; v.i = u & 0xffff0000u; return v.f;
}
__device__ __forceinline__ u32 pk2(float x, float y){
  return ((u32)f2bf(y) << 16) | f2bf(x);
}
__device__ __forceinline__ float fast_sigmoid(float x){ return 1.f/(1.f+__expf(-x)); }
__device__ __forceinline__ float fast_tanh(float x){
  float e = __expf(2.f*x);
  return 1.f - 2.f/(e + 1.f);
}

// bool storage modes: 0=int32, 1=u8, 2=bf16, 3=f32
__device__ __forceinline__ int readBool(const void* p, int i, int m){
  if (m == 0) return ((const int*)p)[i] != 0;
  if (m == 1) return ((const unsigned char*)p)[i] != 0;
  if (m == 2) return ((const u16*)p)[i] != 0;
  return ((const u32*)p)[i] != 0;
}

__device__ __forceinline__ float dot128f(const float* __restrict__ w,
                                         const float* __restrict__ x){
  float acc = 0.f;
  const float4* wp = (const float4*)w;
  #pragma unroll 8
  for (int i = 0; i < 32; i++){
    float4 v = wp[i]; int k = 4*i;
    acc = fmaf(v.x, x[k],   acc);
    acc = fmaf(v.y, x[k+1], acc);
    acc = fmaf(v.z, x[k+2], acc);
    acc = fmaf(v.w, x[k+3], acc);
  }
  return acc;
}

// ---------------------------------------------------------------- sniffer
__global__ void k_sniff2(const u16* __restrict__ embq_raw,
                         const unsigned char* __restrict__ mask_raw,
                         int* __restrict__ flags){
  __shared__ int bad, gt1, m4, b0;
  const int tid = threadIdx.x;
  if (tid == 0){ bad = 0; gt1 = 0; m4 = 0; b0 = 0; }
  __syncthreads();
  for (int i = tid; i < 512; i += 256){
    u16 u = embq_raw[i];
    if (u){ int e = (u >> 7) & 0xFF; if (e < 0x58 || e > 0x7F) atomicAdd(&bad, 1); }
  }
  for (int i = tid; i < 1024; i += 256){
    unsigned char c = mask_raw[i];
    if (c > 1) atomicAdd(&gt1, 1);
    if (c && (i & 3)) atomicAdd(&m4, 1);
    if (c && !(i & 3)) atomicAdd(&b0, 1);
  }
  __syncthreads();
  if (tid == 0){
    flags[0] = (bad >= 16) ? 1 : 0;
    flags[1] = gt1 ? (b0 ? 2 : 3) : (m4 ? 1 : 0);
  }
}

// ---------------------------------------------------------------- convert floats -> f32
#define NCVT 23
struct CvtArgs { const void* s[NCVT]; int off[NCVT+1]; int nreal[NCVT]; };

__global__ void k_cvt(CvtArgs a, const int* __restrict__ flags, float* __restrict__ dst){
  __shared__ int f;
  if (threadIdx.x == 0) f = flags[0];
  __syncthreads();
  int gid = blockIdx.x * 256 + threadIdx.x;
  if (gid >= a.off[NCVT]) return;
  int ai = 0;
  for (int i = 1; i < NCVT; i++) if (gid >= a.off[i]) ai = i;
  int i = gid - a.off[ai];
  float v = 0.f;
  if (i < a.nreal[ai])
    v = f ? ((const float*)a.s[ai])[i] : bf2f(((const u16*)a.s[ai])[i]);
  dst[gid] = v;
}

// ---------------------------------------------------------------- K1: hop aggregation
template<int ROWS>
__device__ __forceinline__ void agg_stage(const float* __restrict__ tmp,
    const float* __restrict__ Wg, const float* __restrict__ bg,
    float* __restrict__ outbuf, int tid)
{
  const int c = tid & 127;
  const int half = tid >> 7;
  constexpr int NR = (ROWS + 1) / 2;
  const bool active = !(ROWS == 1 && half == 1);
  float bias = bg[c];
  float acc[NR];
  #pragma unroll
  for (int i = 0; i < NR; i++) acc[i] = bias;
  if (active){
    const float4* wp = (const float4*)(Wg + c*128);
    #pragma unroll 4
    for (int i4 = 0; i4 < 32; i4++){
      float4 wv = wp[i4];
      int kk = 4*i4;
      #pragma unroll
      for (int i = 0; i < NR; i++){
        int r = (ROWS == 1) ? 0 : (half + 2*i);
        float4 t4 = *(const float4*)(tmp + r*128 + kk);
        acc[i] = fmaf(t4.x, wv.x, acc[i]);
        acc[i] = fmaf(t4.y, wv.y, acc[i]);
        acc[i] = fmaf(t4.z, wv.z, acc[i]);
        acc[i] = fmaf(t4.w, wv.w, acc[i]);
      }
    }
    #pragma unroll
    for (int i = 0; i < NR; i++){
      int r = (ROWS == 1) ? 0 : (half + 2*i);
      outbuf[r*128 + c] = fast_tanh(acc[i]);
    }
  }
}

__launch_bounds__(256, 4)
__global__ void k_agg(const int* __restrict__ question,
                      const int* __restrict__ q_neighbors,
                      const int* __restrict__ s_neighbors,
                      const float* __restrict__ EQ,
                      const float* __restrict__ EC,
                      const float* __restrict__ AW,
                      const float* __restrict__ AB,
                      const float* __restrict__ ALW,
                      const float* __restrict__ ALB,
                      const void* __restrict__ maskp,
                      const int* __restrict__ flags,
                      float* __restrict__ EQREC)
{
  __shared__ __align__(16) float e0[128];
  __shared__ __align__(16) float e1[512];
  __shared__ __align__(16) float e2[2048];
  __shared__ __align__(16) float tmp[2048];
  __shared__ int nn1[4]; __shared__ int nn2[16]; __shared__ int nn3[64];
  const int tid = threadIdx.x;
  const int bs  = blockIdx.x;
  const int n0  = question[bs];
  if (tid < 4)  nn1[tid] = q_neighbors[n0*4 + tid];
  __syncthreads();
  if (tid < 16) nn2[tid] = s_neighbors[nn1[tid>>2]*4 + (tid&3)];
  __syncthreads();
  if (tid < 64) nn3[tid] = q_neighbors[nn2[tid>>2]*4 + (tid&3)];
  for (int o = tid; o < 128; o += 256)  e0[o] = EQ[n0*128 + o];
  __syncthreads();
  for (int o = tid; o < 512; o += 256)  e1[o] = EC[nn1[o>>7]*128 + (o&127)];
  for (int o = tid; o < 2048; o += 256) e2[o] = EQ[nn2[o>>7]*128 + (o&127)];
  __syncthreads();

  auto fill_e0 = [&](){
    for (int o = tid; o < 128; o += 256)
      tmp[o] = 0.25f*(e1[o] + e1[128+o] + e1[256+o] + e1[384+o]) + e0[o];
  };
  auto fill_e1 = [&](){
    for (int o = tid; o < 512; o += 256){
      int r = o >> 7, k = o & 127;
      tmp[o] = 0.25f*(e2[(4*r)*128+k] + e2[(4*r+1)*128+k]
                    + e2[(4*r+2)*128+k] + e2[(4*r+3)*128+k]) + e1[o];
    }
  };

  // i=0: j=0,1,2
  fill_e0(); __syncthreads();
  agg_stage<1>(tmp, AW, AB, e0, tid); __syncthreads();
  fill_e1(); __syncthreads();
  agg_stage<4>(tmp, AW + 16384, AB + 128, e1, tid); __syncthreads();
  for (int o = tid; o < 2048; o += 256){
    int r = o >> 7, k = o & 127;
    float m = 0.25f*( EC[nn3[4*r]*128+k]   + EC[nn3[4*r+1]*128+k]
                    + EC[nn3[4*r+2]*128+k] + EC[nn3[4*r+3]*128+k] );
    tmp[o] = m + e2[o];
  }
  __syncthreads();
  agg_stage<16>(tmp, AW + 32768, AB + 256, e2, tid); __syncthreads();
  // i=1: j=0,1
  fill_e0(); __syncthreads();
  agg_stage<1>(tmp, AW, AB, e0, tid); __syncthreads();
  fill_e1(); __syncthreads();
  agg_stage<4>(tmp, AW + 16384, AB + 128, e1, tid); __syncthreads();
  // i=2: j=0
  fill_e0(); __syncthreads();
  agg_stage<1>(tmp, AW, AB, e0, tid); __syncthreads();
  agg_stage<1>(e0, ALW, ALB, tmp, tid); __syncthreads();
  const int msk = readBool(maskp, bs, flags[1]);
  for (int o = tid; o < 128; o += 256)
    EQREC[bs*128 + o] = msk ? tmp[o] : EQ[n0*128 + o];
}

// ---------------------------------------------------------------- K2: gi1 precompute (K=256)
__launch_bounds__(384, 1)
__global__ void k_gi1(const float* __restrict__ EQREC,
                      const int* __restrict__ response,
                      const float* __restrict__ ECOR,
                      const float* __restrict__ WIH1,
                      const float* __restrict__ BIH1,
                      float* __restrict__ GI1)
{
  const int t  = blockIdx.x;
  const int bg = blockIdx.y;
  const int tid = threadIdx.x;
  __shared__ __align__(16) float X[8][256];
  for (int o = tid; o < 2048; o += 384){
    int bb = o >> 8, k = o & 255;
    int b = bg*8 + bb;
    X[bb][k] = (k < 128) ? EQREC[(b*S_ + t)*128 + k]
                         : ECOR[response[b*S_ + t]*128 + (k - 128)];
  }
  __syncthreads();
  float bias = BIH1[tid];
  float acc[8];
  #pragma unroll
  for (int i = 0; i < 8; i++) acc[i] = bias;
  const float4* wp = (const float4*)(WIH1 + tid*256);
  #pragma unroll 2
  for (int i8 = 0; i8 < 64; i8 += 2){
    float4 v0 = wp[i8], v1 = wp[i8+1];
    float wv[8] = {v0.x,v0.y,v0.z,v0.w,v1.x,v1.y,v1.z,v1.w};
    int k0 = i8*4;
    #pragma unroll
    for (int bb = 0; bb < 8; bb++){
      #pragma unroll
      for (int kq = 0; kq < 8; kq++)
        acc[bb] = fmaf(X[bb][k0 + kq], wv[kq], acc[bb]);
    }
  }
  #pragma unroll
  for (int bb = 0; bb < 8; bb++)
    GI1[(t*32 + bg*8 + bb)*384 + tid] = acc[bb];
}

// ---------------------------------------------------------------- K2b: gi2 precompute (K=128)
// GI2[t,b,j] = bih2[j] + sum_k H1ALL[t,b,k] * wih2[j,k]   (hoisted out of the chain)
__launch_bounds__(384, 1)
__global__ void k_gi2(const float* __restrict__ H1ALL,
                      const float* __restrict__ WIH2,
                      const float* __restrict__ BIH2,
                      float* __restrict__ GI2)
{
  const int t  = blockIdx.x;
  const int bg = blockIdx.y;
  const int tid = threadIdx.x;
  __shared__ __align__(16) float X[8][128];
  for (int o = tid; o < 1024; o += 384){
    int bb = o >> 7, k = o & 127;
    int b = bg*8 + bb;
    X[bb][k] = H1ALL[(t*32 + b)*128 + k];
  }
  __syncthreads();
  float bias = BIH2[tid];
  float acc[8];
  #pragma unroll
  for (int i = 0; i < 8; i++) acc[i] = bias;
  const float4* wp = (const float4*)(WIH2 + tid*128);
  #pragma unroll 2
  for (int i8 = 0; i8 < 32; i8 += 2){
    float4 v0 = wp[i8], v1 = wp[i8+1];
    float wv[8] = {v0.x,v0.y,v0.z,v0.w,v1.x,v1.y,v1.z,v1.w};
    int k0 = i8*4;
    #pragma unroll
    for (int bb = 0; bb < 8; bb++){
      #pragma unroll
      for (int kq = 0; kq < 8; kq++)
        acc[bb] = fmaf(X[bb][k0 + kq], wv[kq], acc[bb]);
    }
  }
  #pragma unroll
  for (int bb = 0; bb < 8; bb++)
    GI2[(t*32 + bg*8 + bb)*384 + tid] = acc[bb];
}

// ---------------------------------------------------------------- K3: scores + top-10
__global__ void k_topk(const int* __restrict__ question,
                       const float* __restrict__ EQ,
                       int* __restrict__ IDX)
{
  const int blk = blockIdx.x;
  const int t = blk >> 5, b = blk & 31;
  const int tid = threadIdx.x;               // 64
  __shared__ __align__(16) float qn[128];
  const int qid = question[b*S_ + t + 1];
  for (int o = tid; o < 128; o += 64) qn[o] = EQ[qid*128 + o];
  __syncthreads();
  float val[4]; int sv[4];
  #pragma unroll
  for (int i = 0; i < 4; i++){
    int s = tid + 64*i;
    sv[i] = s;
    float v = -3.0e38f;
    if (s < S_) v = (s < t) ? dot128f(EQ + question[b*S_ + s]*128, qn) : NEGV;
    val[i] = v;
  }
  for (int r = 0; r < 10; r++){
    float bv = -3.0e38f; int bi = 0x3fffffff;
    #pragma unroll
    for (int i = 0; i < 4; i++){
      if (val[i] > bv || (val[i] == bv && sv[i] < bi)){ bv = val[i]; bi = sv[i]; }
    }
    for (int off = 32; off; off >>= 1){
      float ov = __shfl_down(bv, off);
      int   oi = __shfl_down(bi, off);
      if (ov > bv || (ov == bv && oi < bi)){ bv = ov; bi = oi; }
    }
    int win = __shfl(bi, 0);
    if (tid == 0) IDX[blk*10 + r] = win;
    #pragma unroll
    for (int i = 0; i < 4; i++) if (sv[i] == win) val[i] = -3.0e38f;
  }
}

// ---------------------------------------------------------------- K4a: h1 chain
// ONE weight matrix (whh1) as 64 packed-bf16 u32 in VGPRs (~100 total regs,
// under the allocator's 128 target -> no spill; 192-reg version spilled, r3/r4).
__launch_bounds__(384, 1)
__global__ void k_chain1(const float* __restrict__ GI1,
                         const float* __restrict__ WHH1,
                         const float* __restrict__ BHH1,
                         const float* __restrict__ H1I,
                         float* __restrict__ H1ALL)
{
  const int b = blockIdx.x;
  const int tid = threadIdx.x;
  __shared__ __align__(16) float h[128];
  __shared__ float gh[384];
  if (tid < 128) h[tid] = H1I[b*128 + tid];
  const float bias = BHH1[tid];
  u32 W[64];
  {
    const float4* wp = (const float4*)(WHH1 + tid*128);
    #pragma unroll
    for (int i = 0; i < 32; i++){
      float4 v = wp[i];
      W[2*i]   = pk2(v.x, v.y);
      W[2*i+1] = pk2(v.z, v.w);
    }
  }
  float irN = 0.f, izN = 0.f, innN = 0.f;
  if (tid < 128){
    const float* gp = GI1 + b*384;
    irN = gp[tid]; izN = gp[128+tid]; innN = gp[256+tid];
  }
  __syncthreads();
  for (int t = 0; t < T_; t++){
    const float ir = irN, iz = izN, inn = innN;
    if (t + 1 < T_ && tid < 128){
      const float* gp = GI1 + ((t+1)*32 + b)*384;
      irN = gp[tid]; izN = gp[128+tid]; innN = gp[256+tid];
    }
    float a = bias, ab = 0.f;
    #pragma unroll
    for (int i = 0; i < 32; i++){
      const float4 hv = *(const float4*)(h + 4*i);
      u32 u0 = W[2*i], u1 = W[2*i+1];
      a  = fmaf(lo_(u0), hv.x, a);
      ab = fmaf(hi_(u0), hv.y, ab);
      a  = fmaf(lo_(u1), hv.z, a);
      ab = fmaf(hi_(u1), hv.w, ab);
    }
    gh[tid] = a + ab;
    __syncthreads();
    if (tid < 128){
      float r = fast_sigmoid(ir + gh[tid]);
      float z = fast_sigmoid(iz + gh[128+tid]);
      float n = fast_tanh(inn + r*gh[256+tid]);
      float hn = (1.f - z)*n + z*h[tid];
      h[tid] = hn;
      H1ALL[(t*32 + b)*128 + tid] = hn;
    }
    __syncthreads();
  }
}

// ---------------------------------------------------------------- K4b: h2/g2 chain
__launch_bounds__(384, 1)
__global__ void k_chain2(const float* __restrict__ GI2,
                         const float* __restrict__ WHH2,
                         const float* __restrict__ BHH2,
                         const float* __restrict__ H2I,
                         float* __restrict__ G2)
{
  const int b = blockIdx.x;
  const int tid = threadIdx.x;
  __shared__ __align__(16) float h[128];
  __shared__ float gh[384];
  if (tid < 128) h[tid] = H2I[b*128 + tid];
  const float bias = BHH2[tid];
  u32 W[64];
  {
    const float4* wp = (const float4*)(WHH2 + tid*128);
    #pragma unroll
    for (int i = 0; i < 32; i++){
      float4 v = wp[i];
      W[2*i]   = pk2(v.x, v.y);
      W[2*i+1] = pk2(v.z, v.w);
    }
  }
  float irN = 0.f, izN = 0.f, innN = 0.f;
  if (tid < 128){
    const float* gp = GI2 + b*384;
    irN = gp[tid]; izN = gp[128+tid]; innN = gp[256+tid];
  }
  __syncthreads();
  for (int t = 0; t < T_; t++){
    const float ir = irN, iz = izN, inn = innN;
    if (t + 1 < T_ && tid < 128){
      const float* gp = GI2 + ((t+1)*32 + b)*384;
      irN = gp[tid]; izN = gp[128+tid]; innN = gp[256+tid];
    }
    float a = bias, ab = 0.f;
    #pragma unroll
    for (int i = 0; i < 32; i++){
      const float4 hv = *(const float4*)(h + 4*i);
      u32 u0 = W[2*i], u1 = W[2*i+1];
      a  = fmaf(lo_(u0), hv.x, a);
      ab = fmaf(hi_(u0), hv.y, ab);
      a  = fmaf(lo_(u1), hv.z, a);
      ab = fmaf(hi_(u1), hv.w, ab);
    }
    gh[tid] = a + ab;
    __syncthreads();
    if (tid < 128){
      float r2 = fast_sigmoid(ir + gh[tid]);
      float z2 = fast_sigmoid(iz + gh[128+tid]);
      float n2 = fast_tanh(inn + r2*gh[256+tid]);
      float g = (1.f - z2)*n2 + z2*h[tid];
      G2[(t*32 + b)*128 + tid] = g;
      if (t > 0) h[tid] = g;
    }
    __syncthreads();
  }
}

// ---------------------------------------------------------------- K5: Qp·w_q and Kp·w_k scalars
__device__ __forceinline__ float blockReduce128(float v, float* red, int tid){
  for (int off = 32; off; off >>= 1) v += __shfl_down(v, off);
  if ((tid & 63) == 0) red[tid >> 6] = v;
  __syncthreads();
  float r = red[0] + red[1];
  __syncthreads();
  return r;
}

__global__ void k_qkw(const int* __restrict__ question,
                      const int* __restrict__ qci,
                      const void* __restrict__ qcm,
                      const int* __restrict__ flags,
                      const float* __restrict__ EQ,
                      const float* __restrict__ EC,
                      const float* __restrict__ KW, const float* __restrict__ KB,
                      const float* __restrict__ QW, const float* __restrict__ QB,
                      const float* __restrict__ MW,
                      const float* __restrict__ G2,
                      float* __restrict__ QPW, float* __restrict__ KPWG)
{
  const int blk = blockIdx.x;
  const int t = blk >> 5, b = blk & 31;
  const int tid = threadIdx.x;               // 128
  __shared__ __align__(16) float row[128];
  __shared__ float red[2];
  const int qid = question[b*S_ + t + 1];
  const int bflag = flags[1];
  #pragma unroll 1
  for (int q = 0; q < 5; q++){
    float v = 0.f;
    if (q == 0) v = EQ[qid*128 + tid];
    else if (readBool(qcm, qid*4 + q - 1, bflag))
      v = EC[qci[qid*4 + q - 1]*128 + tid];
    __syncthreads();
    row[tid] = v;
    __syncthreads();
    float acc = KB[tid] + dot128f(KW + tid*128, row);
    float pv  = fast_tanh(acc) * MW[tid];              // w_q
    float s = blockReduce128(pv, red, tid);
    if (tid == 0) QPW[blk*5 + q] = s;
  }
  __syncthreads();
  row[tid] = G2[blk*128 + tid];
  __syncthreads();
  float acc = QB[tid] + dot128f(QW + tid*128, row);
  float pv  = fast_tanh(acc) * MW[128 + tid];          // w_k
  float s = blockReduce128(pv, red, tid);
  if (tid == 0) KPWG[blk] = s;
}

// ---------------------------------------------------------------- K6: predict + output
__global__ void k_pred(const int* __restrict__ question,
                       const int* __restrict__ qci, const void* __restrict__ qcm,
                       const int* __restrict__ flags,
                       const float* __restrict__ EQ, const float* __restrict__ EC,
                       const float* __restrict__ QB, const float* __restrict__ MW,
                       const float* __restrict__ MB,
                       const float* __restrict__ G2,
                       const int* __restrict__ IDX,
                       const float* __restrict__ QPW, const float* __restrict__ KPWG,
                       void* __restrict__ outp)
{
  const int blk = blockIdx.x;
  const int t = blk >> 5, b = blk & 31;
  const int tid = threadIdx.x;               // 64
  __shared__ float hist[11][132];
  __shared__ float qc[5][132];
  __shared__ float og[55];
  __shared__ float kpw[11];
  __shared__ int   idxs[10];
  __shared__ float kpw0s;
  __shared__ float pq[5];
  const int qid = question[b*S_ + t + 1];
  const int bflag = flags[1];
  if (tid < 10) idxs[tid] = IDX[blk*10 + tid];
  __syncthreads();
  for (int o = tid; o < 11*128; o += 64){
    int k = o >> 7, c = o & 127;
    float v;
    if (k == 0) v = G2[blk*128 + c];
    else { int s = idxs[k-1]; v = (s == 0) ? 0.f : G2[(s*32 + b)*128 + c]; }
    hist[k][c] = v;
  }
  for (int o = tid; o < 5*128; o += 64){
    int q = o >> 7, c = o & 127;
    float v = 0.f;
    if (q == 0) v = EQ[qid*128 + c];
    else if (readBool(qcm, qid*4 + q - 1, bflag))
      v = EC[qci[qid*4 + q - 1]*128 + c];
    qc[q][c] = v;
  }
  {
    float pv = fast_tanh(QB[tid])      * MW[128 + tid]
             + fast_tanh(QB[tid + 64]) * MW[128 + tid + 64];
    for (int off = 32; off; off >>= 1) pv += __shfl_down(pv, off);
    if (tid == 0) kpw0s = pv;
  }
  __syncthreads();
  if (tid < 55){
    int q = tid / 11, k = tid % 11;
    float acc = 0.f;
    for (int c = 0; c < 128; c++) acc = fmaf(qc[q][c], hist[k][c], acc);
    og[tid] = acc;
  }
  if (tid < 11){
    float v;
    if (tid == 0) v = KPWG[blk];
    else { int s = idxs[tid-1]; v = (s == 0) ? kpw0s : KPWG[s*32 + b]; }
    kpw[tid] = v;
  }
  __syncthreads();
  if (tid < 5){
    float qw = QPW[blk*5 + tid];
    float bb = MB[0];
    float tv[11];
    #pragma unroll
    for (int k = 0; k < 11; k++){
      int valid = (k == 0) || (idxs[k-1] < t);
      tv[k] = valid ? (qw + kpw[k] + bb) : NEGV;
    }
    float m = tv[0];
    #pragma unroll
    for (int k = 1; k < 11; k++) m = fmaxf(m, tv[k]);
    float den = 0.f, num = 0.f;
    #pragma unroll
    for (int k = 0; k < 11; k++){
      float e = __expf(tv[k] - m);
      den += e;
      num = fmaf(e, og[tid*11 + k], num);
    }
    pq[tid] = num / den;
  }
  __syncthreads();
  if (tid == 0){
    float p = pq[0] + pq[1] + pq[2] + pq[3] + pq[4];
    int col = (t == 0) ? 0 : (t + 1);
    if (flags[0]){
      ((float*)outp)[b*S_ + col] = p;
      if (t == 0) ((float*)outp)[b*S_ + 1] = 0.f;
    } else {
      ((u16*)outp)[b*S_ + col] = f2bf(p);
      if (t == 0) ((u16*)outp)[b*S_ + 1] = (u16)0;
    }
  }
}

// ---------------------------------------------------------------- launcher
extern "C" void kernel_launch(void* const* d_in, const int* in_sizes, int n_in,
                              void* d_out, int out_size, void* d_ws, size_t ws_size,
                              hipStream_t stream)
{
  (void)in_sizes; (void)n_in; (void)out_size; (void)ws_size;
  const int* question      = (const int*)d_in[0];
  const int* response      = (const int*)d_in[1];
  const void* maskp        = d_in[2];
  const int* q_neighbors   = (const int*)d_in[3];
  const int* s_neighbors   = (const int*)d_in[4];
  const int* q_concept_idx = (const int*)d_in[5];
  const void* q_concept_mask = d_in[6];

  static const int CN[NCVT] = {2560000,256000,256,98304,49152,384,384,49152,49152,
                               384,384,49152,384,16384,128,16384,128,16384,128,
                               256,1,4096,4096};
  CvtArgs ca;
  int off = 0;
  for (int i = 0; i < NCVT; i++){
    ca.s[i] = d_in[7 + i];
    ca.nreal[i] = CN[i];
    ca.off[i] = off;
    off += (CN[i] + 3) & ~3;
  }
  ca.off[NCVT] = off;
  const int total = off;

  char* ws = (char*)d_ws;
  size_t wo = 0;
  auto alloc = [&](size_t bytes) -> void* {
    void* p = ws + wo;
    wo = (wo + bytes + 255) & ~(size_t)255;
    return p;
  };
  int*   flags = (int*)  alloc(16);
  float* CVT   = (float*)alloc((size_t)total * 4);
  float* EQREC = (float*)alloc((size_t)B_*S_*D_*4);
  float* GI1   = (float*)alloc((size_t)T_*B_*384*4);
  float* GI2A  = (float*)alloc((size_t)T_*B_*384*4);
  float* H1ALL = (float*)alloc((size_t)T_*B_*D_*4);
  float* G2    = (float*)alloc((size_t)T_*B_*D_*4);
  int*   IDX   = (int*)  alloc((size_t)T_*B_*10*4);
  float* QPW   = (float*)alloc((size_t)T_*B_*5*4);
  float* KPWG  = (float*)alloc((size_t)T_*B_*4);

  const float* EQ   = CVT + ca.off[0];
  const float* EC   = CVT + ca.off[1];
  const float* ECOR = CVT + ca.off[2];
  const float* WIH1 = CVT + ca.off[3];
  const float* WHH1 = CVT + ca.off[4];
  const float* BIH1 = CVT + ca.off[5];
  const float* BHH1 = CVT + ca.off[6];
  const float* WIH2 = CVT + ca.off[7];
  const float* WHH2 = CVT + ca.off[8];
  const float* BIH2 = CVT + ca.off[9];
  const float* BHH2 = CVT + ca.off[10];
  const float* AW   = CVT + ca.off[11];
  const float* AB   = CVT + ca.off[12];
  const float* ALW  = CVT + ca.off[13];
  const float* ALB  = CVT + ca.off[14];
  const float* QW   = CVT + ca.off[15];
  const float* QB   = CVT + ca.off[16];
  const float* KW   = CVT + ca.off[17];
  const float* KB   = CVT + ca.off[18];
  const float* MW   = CVT + ca.off[19];
  const float* MB   = CVT + ca.off[20];
  const float* H1I  = CVT + ca.off[21];
  const float* H2I  = CVT + ca.off[22];

  k_sniff2<<<1, 256, 0, stream>>>((const u16*)d_in[7], (const unsigned char*)maskp, flags);
  k_cvt<<<(total + 255)/256, 256, 0, stream>>>(ca, flags, CVT);
  k_agg<<<B_*S_, 256, 0, stream>>>(question, q_neighbors, s_neighbors, EQ, EC,
                                   AW, AB, ALW, ALB, maskp, flags, EQREC);
  k_gi1<<<dim3(T_, 4), 384, 0, stream>>>(EQREC, response, ECOR, WIH1, BIH1, GI1);
  k_topk<<<T_*B_, 64, 0, stream>>>(question, EQ, IDX);
  k_chain1<<<B_, 384, 0, stream>>>(GI1, WHH1, BHH1, H1I, H1ALL);
  k_gi2<<<dim3(T_, 4), 384, 0, stream>>>(H1ALL, WIH2, BIH2, GI2A);
  k_chain2<<<B_, 384, 0, stream>>>(GI2A, WHH2, BHH2, H2I, G2);
  k_qkw<<<T_*B_, 128, 0, stream>>>(question, q_concept_idx, q_concept_mask, flags,
                                   EQ, EC, KW, KB, QW, QB, MW, G2, QPW, KPWG);
  k_pred<<<T_*B_, 64, 0, stream>>>(question, q_concept_idx, q_concept_mask, flags,
                                   EQ, EC, QB, MW, MB, G2, IDX, QPW, KPWG, d_out);
}